// Round 19
// baseline (139.896 us; speedup 1.0000x reference)
//
#include <hip/hip_runtime.h>

typedef __attribute__((ext_vector_type(8))) short short8;
typedef __attribute__((ext_vector_type(4))) float float4f;
typedef __attribute__((ext_vector_type(4))) unsigned short us4;

#define PITCH 136   // shorts/row in LDS planes
#define ROWS 32     // rows per fwd block (r12 geometry: 1 block/CU confirmed best)
#define LOG_SLOPE -2.302585092994046f   // log(0.1)
#define LN2 0.6931471805599453f
#define NBLK 140    // 12 LU + 128 fwd
#define LDS_BYTES 69760   // 8 planes * 32*136*2 + 128 cnt (LU uses 16KB)
// ws layout (floats): [0] ticket | [2..13] logdet partials | [64..4159] counts
// [4160..5695] fp32 biases | [8192..] W hi/lo ushort planes (TILED layout, r11)
#define WS_BIAS 4160
#define WS_WPLANES 8192
#define NWELEM 196608   // 12 * 16384

__device__ __forceinline__ float bf2f(unsigned int u) {
    return __builtin_bit_cast(float, u << 16);
}
__device__ __forceinline__ unsigned short f2bf(float f) {
    unsigned int x = __builtin_bit_cast(unsigned int, f);
    x += 0x7fff + ((x >> 16) & 1);   // round-to-nearest-even
    return (unsigned short)(x >> 16);
}
__device__ __forceinline__ float4f vmsub(float4f a, float s, float4f b) {
    a[0] -= s * b[0]; a[1] -= s * b[1]; a[2] -= s * b[2]; a[3] -= s * b[3];
    return a;
}
__device__ __forceinline__ float4f vscale(float4f a, float s) {
    a[0] *= s; a[1] *= s; a[2] *= s; a[3] *= s;
    return a;
}

// Barrier with LDS-only drain (r10): orders ds_write/ds_read across waves but
// does NOT force vmcnt(0) — weight prefetch loads stay in flight across the
// barrier; compiler inserts counted vmcnt before first use.
__device__ __forceinline__ void bar_lgkm() {
    asm volatile("s_waitcnt lgkmcnt(0)\n\ts_barrier" ::: "memory");
}

template<int ISF32>
__device__ __forceinline__ float ldv(const void* p, int i) {
    if (ISF32) return ((const float*)p)[i];
    return bf2f(((const unsigned short*)p)[i]);
}

// Per-wave dtype sniff: fp32 weights read as u16 pairs have uniform-random
// mantissa halves; bf16 weights have exponent fields in a narrow band.
__device__ __forceinline__ int detect_f32(const unsigned short* W1u, int lane) {
    unsigned int u = W1u[lane * 2];
    unsigned int e = (u >> 7) & 0xFF;
    int bad = (e < 64) || (e > 135);
    return __ballot(bad) != 0ull;
}

__device__ __forceinline__ float4f mfma16(short8 a, short8 b, float4f c) {
    return __builtin_amdgcn_mfma_f32_16x16x32_bf16(a, b, c, 0, 0, 0);
}

__device__ __forceinline__ void split8(float4f a, float4f b, short8& hi, short8& lo) {
#pragma unroll
    for (int j = 0; j < 4; ++j) {
        float v = a[j]; unsigned short h = f2bf(v);
        hi[j] = (short)h; lo[j] = (short)f2bf(v - bf2f(h));
        v = b[j]; h = f2bf(v);
        hi[4 + j] = (short)h; lo[4 + j] = (short)f2bf(v - bf2f(h));
    }
}

// ---- prep: W -> bf16 hi/lo planes (TILED: one wave's loadW instruction reads
// one contiguous 1KB block, r11), biases -> fp32, zero ticket.
__global__ void k_prep(const void* __restrict__ W1, const void* __restrict__ W2,
                       const void* __restrict__ W3, const void* __restrict__ b1,
                       const void* __restrict__ b2, const void* __restrict__ b3,
                       float* __restrict__ ws) {
    const int tid = threadIdx.x, bid = blockIdx.x;
    const int isf32 = detect_f32((const unsigned short*)W1, tid & 63);
    unsigned short* whi = (unsigned short*)(ws + WS_WPLANES);
    unsigned short* wlo = whi + NWELEM;
    if (bid < 96) {
        int s = (bid * 256 + tid) * 8;        // 96*256*8 = 196608
        int mat = s >> 14, off = s & 16383;   // mat = wsel*4 + layer
        int wsel = mat >> 2;
        const void* Wm = wsel == 0 ? W1 : (wsel == 1 ? W2 : W3);
        int src = (mat & 3) * 16384 + off;
        short8 hi, lo;
        if (isf32) {
            const float* p = (const float*)Wm + src;
            split8(*(const float4f*)p, *(const float4f*)(p + 4), hi, lo);
        } else {
            hi = *(const short8*)((const unsigned short*)Wm + src);
            lo = (short8){0, 0, 0, 0, 0, 0, 0, 0};
        }
        // tiled destination offset (8-short chunk: fixed c, k..k+7)
        int c = off >> 7, k = off & 127;
        int kk = k >> 5, q = (k >> 3) & 3;
        int cb = c >> 4, m = c & 15;
        int noff = kk * 4096 + cb * 512 + m * 32 + q * 8;
        *(short8*)(whi + mat * 16384 + noff) = hi;
        *(short8*)(wlo + mat * 16384 + noff) = lo;
    } else {
        for (int e = tid; e < 1536; e += 256) {
            int bsel = e >> 9, idx = e & 511;
            const void* bp = bsel == 0 ? b1 : (bsel == 1 ? b2 : b3);
            ws[WS_BIAS + e] = isf32 ? ((const float*)bp)[idx]
                                    : bf2f(((const unsigned short*)bp)[idx]);
        }
        if (tid == 0) ((int*)ws)[0] = 0;   // finalize ticket
    }
}

// Weight fragment set. fp32: hi+lo (16 short8 = 64 VGPR). bf16: hi only
// (8 short8 = 32 VGPR) — weight lo planes are exactly zero for bf16, so
// skipping their loads AND the w-lo MFMAs is bit-identical.
template<int ISF32> struct WT { short8 v[ISF32 ? 16 : 8]; };

// Tiled-layout load: per instruction, 64 lanes cover one contiguous 1KB block.
template<int ISF32>
__device__ __forceinline__ WT<ISF32> loadW(const unsigned short* __restrict__ wh,
                                           const unsigned short* __restrict__ wl,
                                           int cb, int mq) {
    WT<ISF32> r;
#pragma unroll
    for (int kk = 0; kk < 4; ++kk) {
        const int o0 = kk * 4096 + cb * 512 + mq;
        const int o1 = o0 + 512;
        if (ISF32) {
            r.v[kk * 4 + 0] = *(const short8*)(wh + o0);
            r.v[kk * 4 + 1] = *(const short8*)(wh + o1);
            r.v[kk * 4 + 2] = *(const short8*)(wl + o0);
            r.v[kk * 4 + 3] = *(const short8*)(wl + o1);
        } else {
            r.v[kk * 2 + 0] = *(const short8*)(wh + o0);
            r.v[kk * 2 + 1] = *(const short8*)(wh + o1);
        }
    }
    return r;
}

// out[ROWS x 128] = act( in[ROWS x 128] @ W^T + bias ); ping-pong planes,
// one lgkm-barrier per matvec. Swapped-operand MFMA (r12): lane holds
// xrow = m and 4 contiguous wcols -> vector (b64) epilogue.
// MODE 0: out = leaky(v) | 1: out = res + v | 2: out = leaky(v)+count | 3: count only
template<int MODE, int DOLOAD, int ISF32>
__device__ __forceinline__ WT<ISF32> matvec(const WT<ISF32>& w,
        const unsigned short* inh, const unsigned short* inl,
        unsigned short* outh, unsigned short* outl,
        const unsigned short* resh, const unsigned short* resl,
        const unsigned short* __restrict__ nwh, const unsigned short* __restrict__ nwl,
        const float* __restrict__ bias,
        int lane, int colb, int* cnt) {
    const int m = lane & 15, q = lane >> 4;
    float4f b0 = *(const float4f*)(bias + colb + q * 4);
    float4f b1 = *(const float4f*)(bias + colb + 16 + q * 4);
    float4f acc[2][2];
    acc[0][0] = b0; acc[0][1] = b1;
    acc[1][0] = b0; acc[1][1] = b1;
    bar_lgkm();   // previous matvec's LDS writes visible; vmcnt NOT drained
    WT<ISF32> wn;
    if constexpr (DOLOAD) {
        wn = loadW<ISF32>(nwh, nwl, colb >> 4, m * 32 + q * 8);   // coalesced prefetch
    }
#pragma unroll
    for (int kk = 0; kk < 4; ++kk) {
        const int kc = kk * 32 + q * 8;
#pragma unroll
        for (int rt = 0; rt < 2; ++rt) {
            short8 xh = *(const short8*)(inh + (rt * 16 + m) * PITCH + kc);
            short8 xl = *(const short8*)(inl + (rt * 16 + m) * PITCH + kc);
            if (ISF32) {
                acc[rt][0] = mfma16(w.v[kk * 4 + 0], xh, acc[rt][0]);
                acc[rt][0] = mfma16(w.v[kk * 4 + 0], xl, acc[rt][0]);
                acc[rt][0] = mfma16(w.v[kk * 4 + 2], xh, acc[rt][0]);
                acc[rt][1] = mfma16(w.v[kk * 4 + 1], xh, acc[rt][1]);
                acc[rt][1] = mfma16(w.v[kk * 4 + 1], xl, acc[rt][1]);
                acc[rt][1] = mfma16(w.v[kk * 4 + 3], xh, acc[rt][1]);
            } else {
                acc[rt][0] = mfma16(w.v[kk * 2 + 0], xh, acc[rt][0]);
                acc[rt][0] = mfma16(w.v[kk * 2 + 0], xl, acc[rt][0]);
                acc[rt][1] = mfma16(w.v[kk * 2 + 1], xh, acc[rt][1]);
                acc[rt][1] = mfma16(w.v[kk * 2 + 1], xl, acc[rt][1]);
            }
        }
    }
    int cc[2] = {0, 0};
#pragma unroll
    for (int rt = 0; rt < 2; ++rt) {
#pragma unroll
        for (int ct = 0; ct < 2; ++ct) {
            float4f v = acc[rt][ct];
            const int o = (rt * 16 + m) * PITCH + colb + ct * 16 + q * 4;
            if (MODE == 1) {
                us4 rh = *(const us4*)(resh + o);
                us4 rl = *(const us4*)(resl + o);
#pragma unroll
                for (int j = 0; j < 4; ++j) v[j] += bf2f(rh[j]) + bf2f(rl[j]);
            }
            if (MODE >= 2) {
#pragma unroll
                for (int j = 0; j < 4; ++j) cc[rt] += (v[j] <= 0.0f) ? 1 : 0;
            }
            if (MODE == 0 || MODE == 2) {
#pragma unroll
                for (int j = 0; j < 4; ++j) v[j] = v[j] > 0.0f ? v[j] : 0.1f * v[j];
            }
            if (MODE != 3) {
                us4 h, l;
#pragma unroll
                for (int j = 0; j < 4; ++j) {
                    unsigned short hh = f2bf(v[j]);
                    h[j] = hh;
                    l[j] = f2bf(v[j] - bf2f(hh));
                }
                *(us4*)(outh + o) = h;
                *(us4*)(outl + o) = l;
            }
        }
    }
    if (MODE >= 2) {
#pragma unroll
        for (int rt = 0; rt < 2; ++rt) {
            int c = cc[rt];
            c += __shfl_xor(c, 16);
            c += __shfl_xor(c, 32);
            if (q == 0) atomicAdd(&cnt[rt * 16 + m], c);
        }
    }
    if constexpr (DOLOAD) return wn;
    else return w;   // unused by callers; keeps a defined value
}

// Per-layer weight-set ledger (fp32: 64 VGPR/set, bf16: 32; max 3 live):
//   h1 uses A=w1[L], loads B=w2[L] | h2 uses B, loads C=w3[L] | res uses C
//   g1 uses A (HELD) | g2 uses B (HELD), loads A=w1[L+1]
template<int ISF32>
__device__ __forceinline__ void fwd(int bid, int tid, int lane, char* ldsb,
                                    const void* x, const float* ws, void* out,
                                    float* wsw) {
    unsigned short* P = (unsigned short*)ldsb;
    unsigned short* Ah = P;
    unsigned short* Al = P + 1 * ROWS * PITCH;
    unsigned short* Bh = P + 2 * ROWS * PITCH;
    unsigned short* Bl = P + 3 * ROWS * PITCH;
    unsigned short* Th = P + 4 * ROWS * PITCH;
    unsigned short* Tl = P + 5 * ROWS * PITCH;
    unsigned short* Uh = P + 6 * ROWS * PITCH;
    unsigned short* Ul = P + 7 * ROWS * PITCH;
    int* cnt = (int*)(P + 8 * ROWS * PITCH);
    const unsigned short* whi = (const unsigned short*)(ws + WS_WPLANES);
    const unsigned short* wlo = whi + NWELEM;
    const float* bias = ws + WS_BIAS;
    const int r0 = bid * ROWS;
    const int m = lane & 15, q = lane >> 4;
    const int colb = (tid >> 6) * 32;
    // prefetch layer-0 w1 while staging x into LDS
    WT<ISF32> wA = loadW<ISF32>(whi, wlo, colb >> 4, m * 32 + q * 8);
    WT<ISF32> wB, wC;
    for (int e = tid; e < ROWS * 128; e += 256) {
        int r = e >> 7, c = e & 127;
        float v = ldv<ISF32>(x, (r0 + r) * 128 + c);
        unsigned short h = f2bf(v);
        Ah[r * PITCH + c] = h;
        Al[r * PITCH + c] = f2bf(v - bf2f(h));
    }
    if (tid < ROWS) cnt[tid] = 0;
    unsigned short *curh = Ah, *curl = Al, *othh = Bh, *othl = Bl;
#pragma unroll 1
    for (int layer = 0; layer < 4; ++layer) {
        const unsigned short* w2h = whi + (4 + layer) * 16384;
        const unsigned short* w2l = wlo + (4 + layer) * 16384;
        const unsigned short* w3h = whi + (8 + layer) * 16384;
        const unsigned short* w3l = wlo + (8 + layer) * 16384;
        const unsigned short* n1h = whi + ((layer + 1) & 3) * 16384;  // next-layer w1
        const unsigned short* n1l = wlo + ((layer + 1) & 3) * 16384;
        const float* b1p = bias + layer * 128;
        const float* b2p = bias + 512 + layer * 128;
        const float* b3p = bias + 1024 + layer * 128;
        wB = matvec<0, 1, ISF32>(wA, curh, curl, Th, Tl, 0, 0, w2h, w2l, b1p, lane, colb, cnt);
        wC = matvec<0, 1, ISF32>(wB, Th, Tl, Uh, Ul, 0, 0, w3h, w3l, b2p, lane, colb, cnt);
        matvec<1, 0, ISF32>(wC, Uh, Ul, othh, othl, curh, curl, 0, 0, b3p, lane, colb, cnt);
        matvec<2, 0, ISF32>(wA, othh, othl, Th, Tl, 0, 0, 0, 0, b1p, lane, colb, cnt);
        wA = matvec<3, 1, ISF32>(wB, Th, Tl, Th, Tl, 0, 0, n1h, n1l, b2p, lane, colb, cnt);
        unsigned short* t;
        t = curh; curh = othh; othh = t;
        t = curl; curl = othl; othl = t;
    }
    bar_lgkm();
    for (int e = tid; e < ROWS * 128; e += 256) {
        int r = e >> 7, c = e & 127;
        float v = bf2f(curh[r * PITCH + c]) + bf2f(curl[r * PITCH + c]);
        if (ISF32) ((float*)out)[(r0 + r) * 128 + c] = v;
        else ((unsigned short*)out)[(r0 + r) * 128 + c] = f2bf(v);
    }
    if (tid < ROWS) wsw[64 + r0 + tid] = (float)cnt[tid];
}

// ---- register-resident unpivoted LU, RANK-8, 256 threads (r19).
// r15 (2x chains -> 2x time) + r16 (rank-8 = rank-4 null) showed LU time
// tracks ISSUED VOLUME. r19 cuts volume: thread (tx) owning cols 4tx..4tx+3
// only needs its V updated while kap < (tx>>1) (its cols are staged into
// colbuf at end of interval (tx>>1)-1; dead cols are read only by dead
// threads' R, whose X updates only dead cols — r6 argument). Thread remap
// tx = tid>>3 (wave-contiguous), ty = tid&7 makes the skip WAVE-granular:
// a fully-dead wave skips the whole trailing block via s_cbranch_execz
// (live wave-intervals 36/64). Dead threads run a panel-only copy so
// logacc stays correct (tid 0 always takes that path). Same (tx,ty) set as
// r16 — algorithm invariant under thread permutation; LDS formulas unchanged.
template<int ISF32>
__device__ __forceinline__ float lu_logdet(int id, int tid, float* lds,
        const void* W1, const void* W2, const void* W3) {
    const int wsel = id % 3;
    const void* Wm = (wsel == 0 ? W1 : (wsel == 1 ? W2 : W3));
    const int ofs = (id / 3) * 16384;
    const int tx = (tid >> 3) & 31, ty = tid & 7;   // r19 remap
    float* rowbuf = lds;          // [2][8][128]: rows K..K+7
    float* colbuf = lds + 2048;   // [2][8][128]: cols K..K+7 packed [jj][ty*16+midx]
    float4f V[16];                // A[ty+8m][4tx..4tx+3]
#pragma unroll
    for (int m = 0; m < 16; ++m) {
        int base = ofs + (ty + 8 * m) * 128 + 4 * tx;
        if (ISF32) {
            V[m] = *(const float4f*)((const float*)Wm + base);
        } else {
            ushort4 u = *(const ushort4*)((const unsigned short*)Wm + base);
            V[m] = (float4f){bf2f(u.x), bf2f(u.y), bf2f(u.z), bf2f(u.w)};
        }
    }
    // stage interval 0: rows 0..7 (every thread: V[0] = row ty); cols 0..7 (tx<2)
    *(float4f*)&rowbuf[ty * 128 + 4 * tx] = V[0];
    if (tx < 2) {
#pragma unroll
        for (int j = 0; j < 4; ++j) {
#pragma unroll
            for (int mg = 0; mg < 4; ++mg) {
                float4f t = {V[mg * 4 + 0][j], V[mg * 4 + 1][j],
                             V[mg * 4 + 2][j], V[mg * 4 + 3][j]};
                *(float4f*)&colbuf[(tx * 4 + j) * 128 + ty * 16 + mg * 4] = t;
            }
        }
    }
    __syncthreads();
    float logacc = 0.0f;
#pragma unroll 1
    for (int kap = 0; kap < 16; ++kap) {
        const int K = kap * 8;
        const int buf = (kap & 1) * 1024;
        if (kap < (tx >> 1)) {
            // LIVE: full panel + R + backsub + rank-8 trailing update
            float4f Da[8], Db[8], R[8];
#pragma unroll
            for (int j = 0; j < 8; ++j) {
                Da[j] = *(const float4f*)&rowbuf[buf + j * 128 + K];
                Db[j] = *(const float4f*)&rowbuf[buf + j * 128 + K + 4];
                R[j]  = *(const float4f*)&rowbuf[buf + j * 128 + 4 * tx];
            }
            float ivv[8];
#pragma unroll
            for (int i = 0; i < 8; ++i) {
                float p = (i < 4) ? Da[i][i] : Db[i][i - 4];
                float inv = 1.0f / p;
                ivv[i] = inv;
                logacc += __log2f(fabsf(p));
#pragma unroll
                for (int j = i + 1; j < 8; ++j) {
                    float l = ((i < 4) ? Da[j][i] : Db[j][i - 4]) * inv;
                    Da[j] = vmsub(Da[j], l, Da[i]);
                    Db[j] = vmsub(Db[j], l, Db[i]);
                    R[j]  = vmsub(R[j],  l, R[i]);
                }
            }
            float4f X[8];
#pragma unroll
            for (int j = 7; j >= 0; --j) {
                float4f t = R[j];
#pragma unroll
                for (int k = j + 1; k < 8; ++k) {
                    float u = (k < 4) ? Da[j][k] : Db[j][k - 4];
                    t = vmsub(t, u, X[k]);
                }
                X[j] = vscale(t, ivv[j]);
            }
#pragma unroll
            for (int mg = 0; mg < 4; ++mg) {
                float4f C[8];
#pragma unroll
                for (int jj = 0; jj < 8; ++jj)
                    C[jj] = *(const float4f*)&colbuf[buf + jj * 128 + ty * 16 + mg * 4];
#pragma unroll
                for (int e = 0; e < 4; ++e) {
                    float4f v = V[mg * 4 + e];
#pragma unroll
                    for (int jj = 0; jj < 8; ++jj)
                        v = vmsub(v, C[jj][e], X[jj]);
                    V[mg * 4 + e] = v;
                }
            }
        } else {
            // DEAD cols: panel-only (identical Da/Db math) to keep logacc exact
            float4f Ea[8], Eb[8];
#pragma unroll
            for (int j = 0; j < 8; ++j) {
                Ea[j] = *(const float4f*)&rowbuf[buf + j * 128 + K];
                Eb[j] = *(const float4f*)&rowbuf[buf + j * 128 + K + 4];
            }
#pragma unroll
            for (int i = 0; i < 8; ++i) {
                float p = (i < 4) ? Ea[i][i] : Eb[i][i - 4];
                float inv = 1.0f / p;
                logacc += __log2f(fabsf(p));
#pragma unroll
                for (int j = i + 1; j < 8; ++j) {
                    float l = ((i < 4) ? Ea[j][i] : Eb[j][i - 4]) * inv;
                    Ea[j] = vmsub(Ea[j], l, Ea[i]);
                    Eb[j] = vmsub(Eb[j], l, Eb[i]);
                }
            }
        }
        // stage next interval (rows/cols K+8..K+15)
        if (kap < 15) {
            const int nbuf = ((kap + 1) & 1) * 1024;
            const int mn = kap + 1;              // uniform m index of next rows
            float4f val;
            switch (mn) {                        // uniform switch, static reg index
            case 1:  val = V[1];  break; case 2:  val = V[2];  break;
            case 3:  val = V[3];  break; case 4:  val = V[4];  break;
            case 5:  val = V[5];  break; case 6:  val = V[6];  break;
            case 7:  val = V[7];  break; case 8:  val = V[8];  break;
            case 9:  val = V[9];  break; case 10: val = V[10]; break;
            case 11: val = V[11]; break; case 12: val = V[12]; break;
            case 13: val = V[13]; break; case 14: val = V[14]; break;
            default: val = V[15]; break;
            }
            *(float4f*)&rowbuf[nbuf + ty * 128 + 4 * tx] = val;   // row ty+8*mn
            if ((tx >> 1) == kap + 1) {          // owners of cols 8mn..8mn+7 (live at kap)
                const int half = (tx & 1) * 4;
#pragma unroll
                for (int j = 0; j < 4; ++j) {
#pragma unroll
                    for (int mg = 0; mg < 4; ++mg) {
                        float4f t = {V[mg * 4 + 0][j], V[mg * 4 + 1][j],
                                     V[mg * 4 + 2][j], V[mg * 4 + 3][j]};
                        *(float4f*)&colbuf[nbuf + (half + j) * 128 + ty * 16 + mg * 4] = t;
                    }
                }
            }
        }
        __syncthreads();   // one barrier per 8 pivots
    }
    return logacc * LN2;
}

__global__ __launch_bounds__(256, 1) void k_main(
        const void* __restrict__ x,
        const void* __restrict__ W1, const void* __restrict__ b1,
        const void* __restrict__ W2, const void* __restrict__ b2,
        const void* __restrict__ W3, const void* __restrict__ b3,
        void* __restrict__ out, float* __restrict__ ws) {
    extern __shared__ __align__(16) char ldsb[];
    __shared__ int s_last;
    const int tid = threadIdx.x;
    const int lane = tid & 63;
    const int isf32 = detect_f32((const unsigned short*)W1, lane);

    if (blockIdx.x < 12) {
        float ld = isf32 ? lu_logdet<1>(blockIdx.x, tid, (float*)ldsb, W1, W2, W3)
                         : lu_logdet<0>(blockIdx.x, tid, (float*)ldsb, W1, W2, W3);
        if (tid == 0) ws[2 + blockIdx.x] = ld;
    } else {
        const int bid = blockIdx.x - 12;
        if (isf32) fwd<1>(bid, tid, lane, ldsb, x, ws, out, ws);
        else       fwd<0>(bid, tid, lane, ldsb, x, ws, out, ws);
    }

    // ---- last-block finalize ----
    __threadfence();
    if (tid == 0) s_last = (atomicAdd((int*)ws, 1) == NBLK - 1);
    __syncthreads();
    if (!s_last) return;
    __threadfence();   // acquire: other blocks' ws writes now visible
    float s = 0.0f;
#pragma unroll
    for (int i = 0; i < 12; ++i) s += ws[2 + i];
    for (int b = tid; b < 4096; b += 256) {
        float v = s + LOG_SLOPE * ws[64 + b];
        if (isf32) ((float*)out)[524288 + b] = v;
        else ((unsigned short*)out)[524288 + b] = f2bf(v);
    }
}

extern "C" void kernel_launch(void* const* d_in, const int* in_sizes, int n_in,
                              void* d_out, int out_size, void* d_ws, size_t ws_size,
                              hipStream_t stream) {
    const void* x  = d_in[0];
    const void* W1 = d_in[1];
    const void* b1 = d_in[2];
    const void* W2 = d_in[3];
    const void* b2 = d_in[4];
    const void* W3 = d_in[5];
    const void* b3 = d_in[6];
    float* ws = (float*)d_ws;

    hipLaunchKernelGGL(k_prep, dim3(97), dim3(256), 0, stream,
                       W1, W2, W3, b1, b2, b3, ws);
    hipLaunchKernelGGL(k_main, dim3(NBLK), dim3(256), LDS_BYTES, stream,
                       x, W1, b1, W2, b2, W3, b3, d_out, ws);
}

// Round 20
// 132.381 us; speedup vs baseline: 1.0568x; 1.0568x over previous
//
#include <hip/hip_runtime.h>

typedef __attribute__((ext_vector_type(8))) short short8;
typedef __attribute__((ext_vector_type(4))) float float4f;
typedef __attribute__((ext_vector_type(4))) unsigned short us4;

#define PITCH 136   // shorts/row in LDS planes
#define ROWS 32     // rows per fwd block (r12 geometry: 1 block/CU confirmed best)
#define LOG_SLOPE -2.302585092994046f   // log(0.1)
#define LN2 0.6931471805599453f
#define NBLK 140    // 12 LU + 128 fwd
#define LDS_BYTES 69760   // 8 planes * 32*136*2 + 128 cnt (LU uses 16KB)
// ws layout (floats): [0] ticket | [1] staging counter | [2..13] logdet partials
// [64..4159] counts | [4160..5695] fp32 biases | [8192..] W hi/lo planes (TILED)
#define WS_BIAS 4160
#define WS_WPLANES 8192
#define NWELEM 196608   // 12 * 16384

__device__ __forceinline__ float bf2f(unsigned int u) {
    return __builtin_bit_cast(float, u << 16);
}
__device__ __forceinline__ unsigned short f2bf(float f) {
    unsigned int x = __builtin_bit_cast(unsigned int, f);
    x += 0x7fff + ((x >> 16) & 1);   // round-to-nearest-even
    return (unsigned short)(x >> 16);
}
__device__ __forceinline__ float4f vmsub(float4f a, float s, float4f b) {
    a[0] -= s * b[0]; a[1] -= s * b[1]; a[2] -= s * b[2]; a[3] -= s * b[3];
    return a;
}
__device__ __forceinline__ float4f vscale(float4f a, float s) {
    a[0] *= s; a[1] *= s; a[2] *= s; a[3] *= s;
    return a;
}

// Barrier with LDS-only drain (r10): orders ds_write/ds_read across waves but
// does NOT force vmcnt(0) — weight prefetch loads stay in flight across the
// barrier; compiler inserts counted vmcnt before first use.
__device__ __forceinline__ void bar_lgkm() {
    asm volatile("s_waitcnt lgkmcnt(0)\n\ts_barrier" ::: "memory");
}

template<int ISF32>
__device__ __forceinline__ float ldv(const void* p, int i) {
    if (ISF32) return ((const float*)p)[i];
    return bf2f(((const unsigned short*)p)[i]);
}

// Per-wave dtype sniff: fp32 weights read as u16 pairs have uniform-random
// mantissa halves; bf16 weights have exponent fields in a narrow band.
__device__ __forceinline__ int detect_f32(const unsigned short* W1u, int lane) {
    unsigned int u = W1u[lane * 2];
    unsigned int e = (u >> 7) & 0xFF;
    int bad = (e < 64) || (e > 135);
    return __ballot(bad) != 0ull;
}

__device__ __forceinline__ float4f mfma16(short8 a, short8 b, float4f c) {
    return __builtin_amdgcn_mfma_f32_16x16x32_bf16(a, b, c, 0, 0, 0);
}

__device__ __forceinline__ void split8(float4f a, float4f b, short8& hi, short8& lo) {
#pragma unroll
    for (int j = 0; j < 4; ++j) {
        float v = a[j]; unsigned short h = f2bf(v);
        hi[j] = (short)h; lo[j] = (short)f2bf(v - bf2f(h));
        v = b[j]; h = f2bf(v);
        hi[4 + j] = (short)h; lo[4 + j] = (short)f2bf(v - bf2f(h));
    }
}

// Weight fragment set. fp32: hi+lo (16 short8 = 64 VGPR). bf16: hi only
// (8 short8 = 32 VGPR) — weight lo planes are exactly zero for bf16, so
// skipping their loads AND the w-lo MFMAs is bit-identical.
template<int ISF32> struct WT { short8 v[ISF32 ? 16 : 8]; };

// Tiled-layout load (r11): per instruction, 64 lanes cover one contiguous 1KB block.
template<int ISF32>
__device__ __forceinline__ WT<ISF32> loadW(const unsigned short* __restrict__ wh,
                                           const unsigned short* __restrict__ wl,
                                           int cb, int mq) {
    WT<ISF32> r;
#pragma unroll
    for (int kk = 0; kk < 4; ++kk) {
        const int o0 = kk * 4096 + cb * 512 + mq;
        const int o1 = o0 + 512;
        if (ISF32) {
            r.v[kk * 4 + 0] = *(const short8*)(wh + o0);
            r.v[kk * 4 + 1] = *(const short8*)(wh + o1);
            r.v[kk * 4 + 2] = *(const short8*)(wl + o0);
            r.v[kk * 4 + 3] = *(const short8*)(wl + o1);
        } else {
            r.v[kk * 2 + 0] = *(const short8*)(wh + o0);
            r.v[kk * 2 + 1] = *(const short8*)(wh + o1);
        }
    }
    return r;
}

// out[ROWS x 128] = act( in[ROWS x 128] @ W^T + bias ); ping-pong planes,
// one lgkm-barrier per matvec. Swapped-operand MFMA (r12): lane holds
// xrow = m and 4 contiguous wcols -> vector (b64) epilogue.
// MODE 0: out = leaky(v) | 1: out = res + v | 2: out = leaky(v)+count | 3: count only
template<int MODE, int DOLOAD, int ISF32>
__device__ __forceinline__ WT<ISF32> matvec(const WT<ISF32>& w,
        const unsigned short* inh, const unsigned short* inl,
        unsigned short* outh, unsigned short* outl,
        const unsigned short* resh, const unsigned short* resl,
        const unsigned short* __restrict__ nwh, const unsigned short* __restrict__ nwl,
        const float* __restrict__ bias,
        int lane, int colb, int* cnt) {
    const int m = lane & 15, q = lane >> 4;
    float4f b0 = *(const float4f*)(bias + colb + q * 4);
    float4f b1 = *(const float4f*)(bias + colb + 16 + q * 4);
    float4f acc[2][2];
    acc[0][0] = b0; acc[0][1] = b1;
    acc[1][0] = b0; acc[1][1] = b1;
    bar_lgkm();   // previous matvec's LDS writes visible; vmcnt NOT drained
    WT<ISF32> wn;
    if constexpr (DOLOAD) {
        wn = loadW<ISF32>(nwh, nwl, colb >> 4, m * 32 + q * 8);   // coalesced prefetch
    }
#pragma unroll
    for (int kk = 0; kk < 4; ++kk) {
        const int kc = kk * 32 + q * 8;
#pragma unroll
        for (int rt = 0; rt < 2; ++rt) {
            short8 xh = *(const short8*)(inh + (rt * 16 + m) * PITCH + kc);
            short8 xl = *(const short8*)(inl + (rt * 16 + m) * PITCH + kc);
            if (ISF32) {
                acc[rt][0] = mfma16(w.v[kk * 4 + 0], xh, acc[rt][0]);
                acc[rt][0] = mfma16(w.v[kk * 4 + 0], xl, acc[rt][0]);
                acc[rt][0] = mfma16(w.v[kk * 4 + 2], xh, acc[rt][0]);
                acc[rt][1] = mfma16(w.v[kk * 4 + 1], xh, acc[rt][1]);
                acc[rt][1] = mfma16(w.v[kk * 4 + 1], xl, acc[rt][1]);
                acc[rt][1] = mfma16(w.v[kk * 4 + 3], xh, acc[rt][1]);
            } else {
                acc[rt][0] = mfma16(w.v[kk * 2 + 0], xh, acc[rt][0]);
                acc[rt][0] = mfma16(w.v[kk * 2 + 0], xl, acc[rt][0]);
                acc[rt][1] = mfma16(w.v[kk * 2 + 1], xh, acc[rt][1]);
                acc[rt][1] = mfma16(w.v[kk * 2 + 1], xl, acc[rt][1]);
            }
        }
    }
    int cc[2] = {0, 0};
#pragma unroll
    for (int rt = 0; rt < 2; ++rt) {
#pragma unroll
        for (int ct = 0; ct < 2; ++ct) {
            float4f v = acc[rt][ct];
            const int o = (rt * 16 + m) * PITCH + colb + ct * 16 + q * 4;
            if (MODE == 1) {
                us4 rh = *(const us4*)(resh + o);
                us4 rl = *(const us4*)(resl + o);
#pragma unroll
                for (int j = 0; j < 4; ++j) v[j] += bf2f(rh[j]) + bf2f(rl[j]);
            }
            if (MODE >= 2) {
#pragma unroll
                for (int j = 0; j < 4; ++j) cc[rt] += (v[j] <= 0.0f) ? 1 : 0;
            }
            if (MODE == 0 || MODE == 2) {
#pragma unroll
                for (int j = 0; j < 4; ++j) v[j] = v[j] > 0.0f ? v[j] : 0.1f * v[j];
            }
            if (MODE != 3) {
                us4 h, l;
#pragma unroll
                for (int j = 0; j < 4; ++j) {
                    unsigned short hh = f2bf(v[j]);
                    h[j] = hh;
                    l[j] = f2bf(v[j] - bf2f(hh));
                }
                *(us4*)(outh + o) = h;
                *(us4*)(outl + o) = l;
            }
        }
    }
    if (MODE >= 2) {
#pragma unroll
        for (int rt = 0; rt < 2; ++rt) {
            int c = cc[rt];
            c += __shfl_xor(c, 16);
            c += __shfl_xor(c, 32);
            if (q == 0) atomicAdd(&cnt[rt * 16 + m], c);
        }
    }
    if constexpr (DOLOAD) return wn;
    else return w;   // unused by callers; keeps a defined value
}

// Per-layer weight-set ledger (fp32: 64 VGPR/set, bf16: 32; max 3 live):
//   h1 uses A=w1[L], loads B=w2[L] | h2 uses B, loads C=w3[L] | res uses C
//   g1 uses A (HELD) | g2 uses B (HELD), loads A=w1[L+1]
// r20: k_prep is merged in — fwd blocks 0..95 stage the tiled planes (one
// 8-short chunk per thread, exact k_prep mapping), block 96 stages biases;
// all 128 fwd blocks release ws[1] and spin to 128 before first loadW.
// Safe: grid 140 < 256 CUs -> all blocks co-resident, spin cannot deadlock.
// LU blocks read raw W and neither stage nor spin.
template<int ISF32>
__device__ __forceinline__ void fwd(int bid, int tid, int lane, char* ldsb,
                                    const void* x,
                                    const void* __restrict__ W1,
                                    const void* __restrict__ W2,
                                    const void* __restrict__ W3,
                                    const void* __restrict__ b1,
                                    const void* __restrict__ b2,
                                    const void* __restrict__ b3,
                                    float* ws, void* out) {
    unsigned short* P = (unsigned short*)ldsb;
    unsigned short* Ah = P;
    unsigned short* Al = P + 1 * ROWS * PITCH;
    unsigned short* Bh = P + 2 * ROWS * PITCH;
    unsigned short* Bl = P + 3 * ROWS * PITCH;
    unsigned short* Th = P + 4 * ROWS * PITCH;
    unsigned short* Tl = P + 5 * ROWS * PITCH;
    unsigned short* Uh = P + 6 * ROWS * PITCH;
    unsigned short* Ul = P + 7 * ROWS * PITCH;
    int* cnt = (int*)(P + 8 * ROWS * PITCH);
    unsigned short* whi = (unsigned short*)(ws + WS_WPLANES);
    unsigned short* wlo = whi + NWELEM;
    const float* bias = ws + WS_BIAS;
    const int r0 = bid * ROWS;
    const int m = lane & 15, q = lane >> 4;
    const int colb = (tid >> 6) * 32;

    // ---- merged staging (was k_prep) ----
    {
        int idx = bid * 256 + tid;            // chunk index
        if (idx < 24576) {                    // 24576 chunks * 8 shorts = NWELEM
            int s = idx * 8;
            int mat = s >> 14, off = s & 16383;
            int wsel = mat >> 2;
            const void* Wm = wsel == 0 ? W1 : (wsel == 1 ? W2 : W3);
            int src = (mat & 3) * 16384 + off;
            short8 hi, lo;
            if (ISF32) {
                const float* p = (const float*)Wm + src;
                split8(*(const float4f*)p, *(const float4f*)(p + 4), hi, lo);
            } else {
                hi = *(const short8*)((const unsigned short*)Wm + src);
                lo = (short8){0, 0, 0, 0, 0, 0, 0, 0};
            }
            int c = off >> 7, k = off & 127;
            int noff = (k >> 5) * 4096 + (c >> 4) * 512 + (c & 15) * 32
                     + ((k >> 3) & 3) * 8;
            *(short8*)(whi + mat * 16384 + noff) = hi;
            *(short8*)(wlo + mat * 16384 + noff) = lo;
        }
        if (bid == 96) {
            for (int e = tid; e < 1536; e += 256) {
                int bsel = e >> 9, bidx = e & 511;
                const void* bp = bsel == 0 ? b1 : (bsel == 1 ? b2 : b3);
                ws[WS_BIAS + e] = ISF32 ? ((const float*)bp)[bidx]
                                        : bf2f(((const unsigned short*)bp)[bidx]);
            }
        }
        __threadfence();
        __syncthreads();
        if (tid == 0) atomicAdd((int*)ws + 1, 1);   // release this block's slice
    }

    // stage x -> LDS while other blocks finish staging (no weight dependency)
    for (int e = tid; e < ROWS * 128; e += 256) {
        int r = e >> 7, c = e & 127;
        float v = ldv<ISF32>(x, (r0 + r) * 128 + c);
        unsigned short h = f2bf(v);
        Ah[r * PITCH + c] = h;
        Al[r * PITCH + c] = f2bf(v - bf2f(h));
    }
    if (tid < ROWS) cnt[tid] = 0;

    // acquire: wait until all 128 fwd blocks staged their slices
    if (tid == 0) {
        while (atomicAdd((int*)ws + 1, 0) < 128) {}
    }
    __syncthreads();
    __threadfence();

    // prefetch layer-0 w1
    WT<ISF32> wA = loadW<ISF32>(whi, wlo, colb >> 4, m * 32 + q * 8);
    WT<ISF32> wB, wC;
    unsigned short *curh = Ah, *curl = Al, *othh = Bh, *othl = Bl;
#pragma unroll 1
    for (int layer = 0; layer < 4; ++layer) {
        const unsigned short* w2h = whi + (4 + layer) * 16384;
        const unsigned short* w2l = wlo + (4 + layer) * 16384;
        const unsigned short* w3h = whi + (8 + layer) * 16384;
        const unsigned short* w3l = wlo + (8 + layer) * 16384;
        const unsigned short* n1h = whi + ((layer + 1) & 3) * 16384;  // next-layer w1
        const unsigned short* n1l = wlo + ((layer + 1) & 3) * 16384;
        const float* b1p = bias + layer * 128;
        const float* b2p = bias + 512 + layer * 128;
        const float* b3p = bias + 1024 + layer * 128;
        wB = matvec<0, 1, ISF32>(wA, curh, curl, Th, Tl, 0, 0, w2h, w2l, b1p, lane, colb, cnt);
        wC = matvec<0, 1, ISF32>(wB, Th, Tl, Uh, Ul, 0, 0, w3h, w3l, b2p, lane, colb, cnt);
        matvec<1, 0, ISF32>(wC, Uh, Ul, othh, othl, curh, curl, 0, 0, b3p, lane, colb, cnt);
        matvec<2, 0, ISF32>(wA, othh, othl, Th, Tl, 0, 0, 0, 0, b1p, lane, colb, cnt);
        wA = matvec<3, 1, ISF32>(wB, Th, Tl, Th, Tl, 0, 0, n1h, n1l, b2p, lane, colb, cnt);
        unsigned short* t;
        t = curh; curh = othh; othh = t;
        t = curl; curl = othl; othl = t;
    }
    bar_lgkm();
    for (int e = tid; e < ROWS * 128; e += 256) {
        int r = e >> 7, c = e & 127;
        float v = bf2f(curh[r * PITCH + c]) + bf2f(curl[r * PITCH + c]);
        if (ISF32) ((float*)out)[(r0 + r) * 128 + c] = v;
        else ((unsigned short*)out)[(r0 + r) * 128 + c] = f2bf(v);
    }
    if (tid < ROWS) ws[64 + r0 + tid] = (float)cnt[tid];
}

// ---- register-resident unpivoted LU, RANK-4 per barrier (32 intervals).
// Trailing update via V -= C_raw * (Upanel^{-1} R) (r6 identity). Reads raw W.
template<int ISF32>
__device__ __forceinline__ float lu_logdet(int id, int tid, float* lds,
        const void* W1, const void* W2, const void* W3) {
    const int wsel = id % 3;
    const void* Wm = (wsel == 0 ? W1 : (wsel == 1 ? W2 : W3));
    const int ofs = (id / 3) * 16384;
    const int tx = tid & 31, ty = tid >> 5;
    float* rowbuf = lds;          // [2][4][128]: rows K..K+3
    float* colbuf = lds + 1024;   // [2][4][128]: cols K..K+3 packed [j][ty*16+m]
    float4f V[16];                // A[ty+8m][4tx..4tx+3]
#pragma unroll
    for (int m = 0; m < 16; ++m) {
        int base = ofs + (ty + 8 * m) * 128 + 4 * tx;
        if (ISF32) {
            V[m] = *(const float4f*)((const float*)Wm + base);
        } else {
            ushort4 u = *(const ushort4*)((const unsigned short*)Wm + base);
            V[m] = (float4f){bf2f(u.x), bf2f(u.y), bf2f(u.z), bf2f(u.w)};
        }
    }
    if (ty < 4) *(float4f*)&rowbuf[ty * 128 + 4 * tx] = V[0];
    if (tx == 0) {
#pragma unroll
        for (int j = 0; j < 4; ++j) {
#pragma unroll
            for (int mg = 0; mg < 4; ++mg) {
                float4f t = {V[mg * 4 + 0][j], V[mg * 4 + 1][j],
                             V[mg * 4 + 2][j], V[mg * 4 + 3][j]};
                *(float4f*)&colbuf[j * 128 + ty * 16 + mg * 4] = t;
            }
        }
    }
    __syncthreads();
    float logacc = 0.0f;
#pragma unroll 1
    for (int kap = 0; kap < 32; ++kap) {
        const int K = kap * 4;
        const int buf = (kap & 1) * 512;
        float4f D[4], R[4], C[4][4];
#pragma unroll
        for (int j = 0; j < 4; ++j) {
            D[j] = *(const float4f*)&rowbuf[buf + j * 128 + K];       // broadcast
            R[j] = *(const float4f*)&rowbuf[buf + j * 128 + 4 * tx];
#pragma unroll
            for (int mg = 0; mg < 4; ++mg)
                C[j][mg] = *(const float4f*)&colbuf[buf + j * 128 + ty * 16 + mg * 4];
        }
        float p0 = D[0][0], i0 = 1.0f / p0;
        float l10 = D[1][0] * i0, l20 = D[2][0] * i0, l30 = D[3][0] * i0;
        D[1] = vmsub(D[1], l10, D[0]); R[1] = vmsub(R[1], l10, R[0]);
        D[2] = vmsub(D[2], l20, D[0]); R[2] = vmsub(R[2], l20, R[0]);
        D[3] = vmsub(D[3], l30, D[0]); R[3] = vmsub(R[3], l30, R[0]);
        float p1 = D[1][1], i1 = 1.0f / p1;
        float l21 = D[2][1] * i1, l31 = D[3][1] * i1;
        D[2] = vmsub(D[2], l21, D[1]); R[2] = vmsub(R[2], l21, R[1]);
        D[3] = vmsub(D[3], l31, D[1]); R[3] = vmsub(R[3], l31, R[1]);
        float p2 = D[2][2], i2 = 1.0f / p2;
        float l32 = D[3][2] * i2;
        D[3] = vmsub(D[3], l32, D[2]); R[3] = vmsub(R[3], l32, R[2]);
        float p3 = D[3][3], i3 = 1.0f / p3;
        logacc += __log2f(fabsf(p0)) + __log2f(fabsf(p1))
                + __log2f(fabsf(p2)) + __log2f(fabsf(p3));
        float4f X3 = vscale(R[3], i3);
        float4f X2 = vscale(vmsub(R[2], D[2][3], X3), i2);
        float4f X1 = vscale(vmsub(vmsub(R[1], D[1][2], X2), D[1][3], X3), i1);
        float4f X0 = vscale(vmsub(vmsub(vmsub(R[0], D[0][1], X1),
                                        D[0][2], X2), D[0][3], X3), i0);
#pragma unroll
        for (int mg = 0; mg < 4; ++mg) {
#pragma unroll
            for (int e = 0; e < 4; ++e) {
                float4f v = V[mg * 4 + e];
                v = vmsub(v, C[0][mg][e], X0);
                v = vmsub(v, C[1][mg][e], X1);
                v = vmsub(v, C[2][mg][e], X2);
                v = vmsub(v, C[3][mg][e], X3);
                V[mg * 4 + e] = v;
            }
        }
        if (kap < 31) {
            const int nbuf = ((kap + 1) & 1) * 512;
            const int tb = (kap & 1) ? 0 : 4;
            const int mn = (kap + 1) >> 1;
            if (ty >= tb && ty < tb + 4) {
                float4f val;
                switch (mn) {
                case 0:  val = V[0];  break; case 1:  val = V[1];  break;
                case 2:  val = V[2];  break; case 3:  val = V[3];  break;
                case 4:  val = V[4];  break; case 5:  val = V[5];  break;
                case 6:  val = V[6];  break; case 7:  val = V[7];  break;
                case 8:  val = V[8];  break; case 9:  val = V[9];  break;
                case 10: val = V[10]; break; case 11: val = V[11]; break;
                case 12: val = V[12]; break; case 13: val = V[13]; break;
                case 14: val = V[14]; break; default: val = V[15]; break;
                }
                *(float4f*)&rowbuf[nbuf + (ty - tb) * 128 + 4 * tx] = val;
            }
            if (tx == kap + 1) {
#pragma unroll
                for (int j = 0; j < 4; ++j) {
#pragma unroll
                    for (int mg = 0; mg < 4; ++mg) {
                        float4f t = {V[mg * 4 + 0][j], V[mg * 4 + 1][j],
                                     V[mg * 4 + 2][j], V[mg * 4 + 3][j]};
                        *(float4f*)&colbuf[nbuf + j * 128 + ty * 16 + mg * 4] = t;
                    }
                }
            }
        }
        __syncthreads();
    }
    return logacc * LN2;
}

__global__ __launch_bounds__(256, 1) void k_main(
        const void* __restrict__ x,
        const void* __restrict__ W1, const void* __restrict__ b1,
        const void* __restrict__ W2, const void* __restrict__ b2,
        const void* __restrict__ W3, const void* __restrict__ b3,
        void* __restrict__ out, float* __restrict__ ws) {
    extern __shared__ __align__(16) char ldsb[];
    __shared__ int s_last;
    const int tid = threadIdx.x;
    const int lane = tid & 63;
    const int isf32 = detect_f32((const unsigned short*)W1, lane);

    if (blockIdx.x < 12) {
        float ld = isf32 ? lu_logdet<1>(blockIdx.x, tid, (float*)ldsb, W1, W2, W3)
                         : lu_logdet<0>(blockIdx.x, tid, (float*)ldsb, W1, W2, W3);
        if (tid == 0) ws[2 + blockIdx.x] = ld;
    } else {
        const int bid = blockIdx.x - 12;
        if (isf32) fwd<1>(bid, tid, lane, ldsb, x, W1, W2, W3, b1, b2, b3, ws, out);
        else       fwd<0>(bid, tid, lane, ldsb, x, W1, W2, W3, b1, b2, b3, ws, out);
    }

    // ---- last-block finalize ----
    __threadfence();
    if (tid == 0) s_last = (atomicAdd((int*)ws, 1) == NBLK - 1);
    __syncthreads();
    if (!s_last) return;
    __threadfence();   // acquire: other blocks' ws writes now visible
    float s = 0.0f;
#pragma unroll
    for (int i = 0; i < 12; ++i) s += ws[2 + i];
    for (int b = tid; b < 4096; b += 256) {
        float v = s + LOG_SLOPE * ws[64 + b];
        if (isf32) ((float*)out)[524288 + b] = v;
        else ((unsigned short*)out)[524288 + b] = f2bf(v);
    }
}

extern "C" void kernel_launch(void* const* d_in, const int* in_sizes, int n_in,
                              void* d_out, int out_size, void* d_ws, size_t ws_size,
                              hipStream_t stream) {
    const void* x  = d_in[0];
    const void* W1 = d_in[1];
    const void* b1 = d_in[2];
    const void* W2 = d_in[3];
    const void* b2 = d_in[4];
    const void* W3 = d_in[5];
    const void* b3 = d_in[6];
    float* ws = (float*)d_ws;

    // zero ticket (ws[0]) + staging counter (ws[1]); graph-capture-safe
    hipMemsetAsync(ws, 0, 8, stream);
    hipLaunchKernelGGL(k_main, dim3(NBLK), dim3(256), LDS_BYTES, stream,
                       x, W1, b1, W2, b2, W3, b3, d_out, ws);
}

// Round 21
// 119.080 us; speedup vs baseline: 1.1748x; 1.1117x over previous
//
#include <hip/hip_runtime.h>

typedef __attribute__((ext_vector_type(8))) short short8;
typedef __attribute__((ext_vector_type(4))) float float4f;
typedef __attribute__((ext_vector_type(4))) unsigned short us4;

#define PITCH 136   // shorts/row in LDS planes
#define ROWS 32     // rows per fwd block (r12 geometry: 1 block/CU confirmed best)
#define LOG_SLOPE -2.302585092994046f   // log(0.1)
#define LN2 0.6931471805599453f
#define NBLK 140    // 12 LU + 128 fwd
#define LDS_BYTES 69760   // 8 planes * 32*136*2 + 128 cnt (LU uses 16KB)
// ws layout (floats): [0] ticket | [2..13] logdet partials | [64..4159] counts
// [4160..5695] fp32 biases | [8192..] W hi/lo ushort planes (TILED layout, r11)
#define WS_BIAS 4160
#define WS_WPLANES 8192
#define NWELEM 196608   // 12 * 16384

__device__ __forceinline__ float bf2f(unsigned int u) {
    return __builtin_bit_cast(float, u << 16);
}
__device__ __forceinline__ unsigned short f2bf(float f) {
    unsigned int x = __builtin_bit_cast(unsigned int, f);
    x += 0x7fff + ((x >> 16) & 1);   // round-to-nearest-even
    return (unsigned short)(x >> 16);
}
__device__ __forceinline__ float4f vmsub(float4f a, float s, float4f b) {
    a[0] -= s * b[0]; a[1] -= s * b[1]; a[2] -= s * b[2]; a[3] -= s * b[3];
    return a;
}
__device__ __forceinline__ float4f vscale(float4f a, float s) {
    a[0] *= s; a[1] *= s; a[2] *= s; a[3] *= s;
    return a;
}

// Barrier with LDS-only drain (r10): orders ds_write/ds_read across waves but
// does NOT force vmcnt(0) — weight prefetch loads stay in flight across the
// barrier; compiler inserts counted vmcnt before first use.
__device__ __forceinline__ void bar_lgkm() {
    asm volatile("s_waitcnt lgkmcnt(0)\n\ts_barrier" ::: "memory");
}

template<int ISF32>
__device__ __forceinline__ float ldv(const void* p, int i) {
    if (ISF32) return ((const float*)p)[i];
    return bf2f(((const unsigned short*)p)[i]);
}

// Per-wave dtype sniff: fp32 weights read as u16 pairs have uniform-random
// mantissa halves; bf16 weights have exponent fields in a narrow band.
__device__ __forceinline__ int detect_f32(const unsigned short* W1u, int lane) {
    unsigned int u = W1u[lane * 2];
    unsigned int e = (u >> 7) & 0xFF;
    int bad = (e < 64) || (e > 135);
    return __ballot(bad) != 0ull;
}

__device__ __forceinline__ float4f mfma16(short8 a, short8 b, float4f c) {
    return __builtin_amdgcn_mfma_f32_16x16x32_bf16(a, b, c, 0, 0, 0);
}

__device__ __forceinline__ void split8(float4f a, float4f b, short8& hi, short8& lo) {
#pragma unroll
    for (int j = 0; j < 4; ++j) {
        float v = a[j]; unsigned short h = f2bf(v);
        hi[j] = (short)h; lo[j] = (short)f2bf(v - bf2f(h));
        v = b[j]; h = f2bf(v);
        hi[4 + j] = (short)h; lo[4 + j] = (short)f2bf(v - bf2f(h));
    }
}

// ---- prep: W -> bf16 hi/lo planes (TILED: one wave's loadW instruction reads
// one contiguous 1KB block, r11), biases -> fp32, zero ticket.
__global__ void k_prep(const void* __restrict__ W1, const void* __restrict__ W2,
                       const void* __restrict__ W3, const void* __restrict__ b1,
                       const void* __restrict__ b2, const void* __restrict__ b3,
                       float* __restrict__ ws) {
    const int tid = threadIdx.x, bid = blockIdx.x;
    const int isf32 = detect_f32((const unsigned short*)W1, tid & 63);
    unsigned short* whi = (unsigned short*)(ws + WS_WPLANES);
    unsigned short* wlo = whi + NWELEM;
    if (bid < 96) {
        int s = (bid * 256 + tid) * 8;        // 96*256*8 = 196608
        int mat = s >> 14, off = s & 16383;   // mat = wsel*4 + layer
        int wsel = mat >> 2;
        const void* Wm = wsel == 0 ? W1 : (wsel == 1 ? W2 : W3);
        int src = (mat & 3) * 16384 + off;
        short8 hi, lo;
        if (isf32) {
            const float* p = (const float*)Wm + src;
            split8(*(const float4f*)p, *(const float4f*)(p + 4), hi, lo);
        } else {
            hi = *(const short8*)((const unsigned short*)Wm + src);
            lo = (short8){0, 0, 0, 0, 0, 0, 0, 0};
        }
        // tiled destination offset (8-short chunk: fixed c, k..k+7)
        int c = off >> 7, k = off & 127;
        int kk = k >> 5, q = (k >> 3) & 3;
        int cb = c >> 4, m = c & 15;
        int noff = kk * 4096 + cb * 512 + m * 32 + q * 8;
        *(short8*)(whi + mat * 16384 + noff) = hi;
        *(short8*)(wlo + mat * 16384 + noff) = lo;
    } else {
        for (int e = tid; e < 1536; e += 256) {
            int bsel = e >> 9, idx = e & 511;
            const void* bp = bsel == 0 ? b1 : (bsel == 1 ? b2 : b3);
            ws[WS_BIAS + e] = isf32 ? ((const float*)bp)[idx]
                                    : bf2f(((const unsigned short*)bp)[idx]);
        }
        if (tid == 0) ((int*)ws)[0] = 0;   // finalize ticket
    }
}

// Weight fragment set. fp32: hi+lo (16 short8 = 64 VGPR). bf16: hi only
// (8 short8 = 32 VGPR) — weight lo planes are exactly zero for bf16, so
// skipping their loads AND the w-lo MFMAs is bit-identical.
template<int ISF32> struct WT { short8 v[ISF32 ? 16 : 8]; };

// Tiled-layout load: per instruction, 64 lanes cover one contiguous 1KB block.
template<int ISF32>
__device__ __forceinline__ WT<ISF32> loadW(const unsigned short* __restrict__ wh,
                                           const unsigned short* __restrict__ wl,
                                           int cb, int mq) {
    WT<ISF32> r;
#pragma unroll
    for (int kk = 0; kk < 4; ++kk) {
        const int o0 = kk * 4096 + cb * 512 + mq;
        const int o1 = o0 + 512;
        if (ISF32) {
            r.v[kk * 4 + 0] = *(const short8*)(wh + o0);
            r.v[kk * 4 + 1] = *(const short8*)(wh + o1);
            r.v[kk * 4 + 2] = *(const short8*)(wl + o0);
            r.v[kk * 4 + 3] = *(const short8*)(wl + o1);
        } else {
            r.v[kk * 2 + 0] = *(const short8*)(wh + o0);
            r.v[kk * 2 + 1] = *(const short8*)(wh + o1);
        }
    }
    return r;
}

// out[ROWS x 128] = act( in[ROWS x 128] @ W^T + bias ); ping-pong planes,
// one lgkm-barrier per matvec. Swapped-operand MFMA (r12): lane holds
// xrow = m and 4 contiguous wcols -> vector (b64) epilogue.
// MODE 0: out = leaky(v) | 1: out = res + v | 2: out = leaky(v)+count | 3: count only
template<int MODE, int DOLOAD, int ISF32>
__device__ __forceinline__ WT<ISF32> matvec(const WT<ISF32>& w,
        const unsigned short* inh, const unsigned short* inl,
        unsigned short* outh, unsigned short* outl,
        const unsigned short* resh, const unsigned short* resl,
        const unsigned short* __restrict__ nwh, const unsigned short* __restrict__ nwl,
        const float* __restrict__ bias,
        int lane, int colb, int* cnt) {
    const int m = lane & 15, q = lane >> 4;
    float4f b0 = *(const float4f*)(bias + colb + q * 4);
    float4f b1 = *(const float4f*)(bias + colb + 16 + q * 4);
    float4f acc[2][2];
    acc[0][0] = b0; acc[0][1] = b1;
    acc[1][0] = b0; acc[1][1] = b1;
    bar_lgkm();   // previous matvec's LDS writes visible; vmcnt NOT drained
    WT<ISF32> wn;
    if constexpr (DOLOAD) {
        wn = loadW<ISF32>(nwh, nwl, colb >> 4, m * 32 + q * 8);   // coalesced prefetch
    }
#pragma unroll
    for (int kk = 0; kk < 4; ++kk) {
        const int kc = kk * 32 + q * 8;
#pragma unroll
        for (int rt = 0; rt < 2; ++rt) {
            short8 xh = *(const short8*)(inh + (rt * 16 + m) * PITCH + kc);
            short8 xl = *(const short8*)(inl + (rt * 16 + m) * PITCH + kc);
            if (ISF32) {
                acc[rt][0] = mfma16(w.v[kk * 4 + 0], xh, acc[rt][0]);
                acc[rt][0] = mfma16(w.v[kk * 4 + 0], xl, acc[rt][0]);
                acc[rt][0] = mfma16(w.v[kk * 4 + 2], xh, acc[rt][0]);
                acc[rt][1] = mfma16(w.v[kk * 4 + 1], xh, acc[rt][1]);
                acc[rt][1] = mfma16(w.v[kk * 4 + 1], xl, acc[rt][1]);
                acc[rt][1] = mfma16(w.v[kk * 4 + 3], xh, acc[rt][1]);
            } else {
                acc[rt][0] = mfma16(w.v[kk * 2 + 0], xh, acc[rt][0]);
                acc[rt][0] = mfma16(w.v[kk * 2 + 0], xl, acc[rt][0]);
                acc[rt][1] = mfma16(w.v[kk * 2 + 1], xh, acc[rt][1]);
                acc[rt][1] = mfma16(w.v[kk * 2 + 1], xl, acc[rt][1]);
            }
        }
    }
    int cc[2] = {0, 0};
#pragma unroll
    for (int rt = 0; rt < 2; ++rt) {
#pragma unroll
        for (int ct = 0; ct < 2; ++ct) {
            float4f v = acc[rt][ct];
            const int o = (rt * 16 + m) * PITCH + colb + ct * 16 + q * 4;
            if (MODE == 1) {
                us4 rh = *(const us4*)(resh + o);
                us4 rl = *(const us4*)(resl + o);
#pragma unroll
                for (int j = 0; j < 4; ++j) v[j] += bf2f(rh[j]) + bf2f(rl[j]);
            }
            if (MODE >= 2) {
#pragma unroll
                for (int j = 0; j < 4; ++j) cc[rt] += (v[j] <= 0.0f) ? 1 : 0;
            }
            if (MODE == 0 || MODE == 2) {
#pragma unroll
                for (int j = 0; j < 4; ++j) v[j] = v[j] > 0.0f ? v[j] : 0.1f * v[j];
            }
            if (MODE != 3) {
                us4 h, l;
#pragma unroll
                for (int j = 0; j < 4; ++j) {
                    unsigned short hh = f2bf(v[j]);
                    h[j] = hh;
                    l[j] = f2bf(v[j] - bf2f(hh));
                }
                *(us4*)(outh + o) = h;
                *(us4*)(outl + o) = l;
            }
        }
    }
    if (MODE >= 2) {
#pragma unroll
        for (int rt = 0; rt < 2; ++rt) {
            int c = cc[rt];
            c += __shfl_xor(c, 16);
            c += __shfl_xor(c, 32);
            if (q == 0) atomicAdd(&cnt[rt * 16 + m], c);
        }
    }
    if constexpr (DOLOAD) return wn;
    else return w;   // unused by callers; keeps a defined value
}

// Per-layer weight-set ledger (fp32: 64 VGPR/set, bf16: 32; max 3 live):
//   h1 uses A=w1[L], loads B=w2[L] | h2 uses B, loads C=w3[L] | res uses C
//   g1 uses A (HELD) | g2 uses B (HELD), loads A=w1[L+1]
template<int ISF32>
__device__ __forceinline__ void fwd(int bid, int tid, int lane, char* ldsb,
                                    const void* x, const float* ws, void* out,
                                    float* wsw) {
    unsigned short* P = (unsigned short*)ldsb;
    unsigned short* Ah = P;
    unsigned short* Al = P + 1 * ROWS * PITCH;
    unsigned short* Bh = P + 2 * ROWS * PITCH;
    unsigned short* Bl = P + 3 * ROWS * PITCH;
    unsigned short* Th = P + 4 * ROWS * PITCH;
    unsigned short* Tl = P + 5 * ROWS * PITCH;
    unsigned short* Uh = P + 6 * ROWS * PITCH;
    unsigned short* Ul = P + 7 * ROWS * PITCH;
    int* cnt = (int*)(P + 8 * ROWS * PITCH);
    const unsigned short* whi = (const unsigned short*)(ws + WS_WPLANES);
    const unsigned short* wlo = whi + NWELEM;
    const float* bias = ws + WS_BIAS;
    const int r0 = bid * ROWS;
    const int m = lane & 15, q = lane >> 4;
    const int colb = (tid >> 6) * 32;
    // prefetch layer-0 w1 while staging x into LDS
    WT<ISF32> wA = loadW<ISF32>(whi, wlo, colb >> 4, m * 32 + q * 8);
    WT<ISF32> wB, wC;
    for (int e = tid; e < ROWS * 128; e += 256) {
        int r = e >> 7, c = e & 127;
        float v = ldv<ISF32>(x, (r0 + r) * 128 + c);
        unsigned short h = f2bf(v);
        Ah[r * PITCH + c] = h;
        Al[r * PITCH + c] = f2bf(v - bf2f(h));
    }
    if (tid < ROWS) cnt[tid] = 0;
    unsigned short *curh = Ah, *curl = Al, *othh = Bh, *othl = Bl;
#pragma unroll 1
    for (int layer = 0; layer < 4; ++layer) {
        const unsigned short* w2h = whi + (4 + layer) * 16384;
        const unsigned short* w2l = wlo + (4 + layer) * 16384;
        const unsigned short* w3h = whi + (8 + layer) * 16384;
        const unsigned short* w3l = wlo + (8 + layer) * 16384;
        const unsigned short* n1h = whi + ((layer + 1) & 3) * 16384;  // next-layer w1
        const unsigned short* n1l = wlo + ((layer + 1) & 3) * 16384;
        const float* b1p = bias + layer * 128;
        const float* b2p = bias + 512 + layer * 128;
        const float* b3p = bias + 1024 + layer * 128;
        wB = matvec<0, 1, ISF32>(wA, curh, curl, Th, Tl, 0, 0, w2h, w2l, b1p, lane, colb, cnt);
        wC = matvec<0, 1, ISF32>(wB, Th, Tl, Uh, Ul, 0, 0, w3h, w3l, b2p, lane, colb, cnt);
        matvec<1, 0, ISF32>(wC, Uh, Ul, othh, othl, curh, curl, 0, 0, b3p, lane, colb, cnt);
        matvec<2, 0, ISF32>(wA, othh, othl, Th, Tl, 0, 0, 0, 0, b1p, lane, colb, cnt);
        wA = matvec<3, 1, ISF32>(wB, Th, Tl, Th, Tl, 0, 0, n1h, n1l, b2p, lane, colb, cnt);
        unsigned short* t;
        t = curh; curh = othh; othh = t;
        t = curl; curl = othl; othl = t;
    }
    bar_lgkm();
    for (int e = tid; e < ROWS * 128; e += 256) {
        int r = e >> 7, c = e & 127;
        float v = bf2f(curh[r * PITCH + c]) + bf2f(curl[r * PITCH + c]);
        if (ISF32) ((float*)out)[(r0 + r) * 128 + c] = v;
        else ((unsigned short*)out)[(r0 + r) * 128 + c] = f2bf(v);
    }
    if (tid < ROWS) wsw[64 + r0 + tid] = (float)cnt[tid];
}

// ---- register-resident unpivoted LU, RANK-4 per barrier (32 intervals).
// Trailing update via V -= C_raw * (Upanel^{-1} R) (r6 identity). Reads raw W.
template<int ISF32>
__device__ __forceinline__ float lu_logdet(int id, int tid, float* lds,
        const void* W1, const void* W2, const void* W3) {
    const int wsel = id % 3;
    const void* Wm = (wsel == 0 ? W1 : (wsel == 1 ? W2 : W3));
    const int ofs = (id / 3) * 16384;
    const int tx = tid & 31, ty = tid >> 5;
    float* rowbuf = lds;          // [2][4][128]: rows K..K+3
    float* colbuf = lds + 1024;   // [2][4][128]: cols K..K+3 packed [j][ty*16+m]
    float4f V[16];                // A[ty+8m][4tx..4tx+3]
#pragma unroll
    for (int m = 0; m < 16; ++m) {
        int base = ofs + (ty + 8 * m) * 128 + 4 * tx;
        if (ISF32) {
            V[m] = *(const float4f*)((const float*)Wm + base);
        } else {
            ushort4 u = *(const ushort4*)((const unsigned short*)Wm + base);
            V[m] = (float4f){bf2f(u.x), bf2f(u.y), bf2f(u.z), bf2f(u.w)};
        }
    }
    if (ty < 4) *(float4f*)&rowbuf[ty * 128 + 4 * tx] = V[0];
    if (tx == 0) {
#pragma unroll
        for (int j = 0; j < 4; ++j) {
#pragma unroll
            for (int mg = 0; mg < 4; ++mg) {
                float4f t = {V[mg * 4 + 0][j], V[mg * 4 + 1][j],
                             V[mg * 4 + 2][j], V[mg * 4 + 3][j]};
                *(float4f*)&colbuf[j * 128 + ty * 16 + mg * 4] = t;
            }
        }
    }
    __syncthreads();
    float logacc = 0.0f;
#pragma unroll 1
    for (int kap = 0; kap < 32; ++kap) {
        const int K = kap * 4;
        const int buf = (kap & 1) * 512;
        float4f D[4], R[4], C[4][4];
#pragma unroll
        for (int j = 0; j < 4; ++j) {
            D[j] = *(const float4f*)&rowbuf[buf + j * 128 + K];       // broadcast
            R[j] = *(const float4f*)&rowbuf[buf + j * 128 + 4 * tx];
#pragma unroll
            for (int mg = 0; mg < 4; ++mg)
                C[j][mg] = *(const float4f*)&colbuf[buf + j * 128 + ty * 16 + mg * 4];
        }
        float p0 = D[0][0], i0 = 1.0f / p0;
        float l10 = D[1][0] * i0, l20 = D[2][0] * i0, l30 = D[3][0] * i0;
        D[1] = vmsub(D[1], l10, D[0]); R[1] = vmsub(R[1], l10, R[0]);
        D[2] = vmsub(D[2], l20, D[0]); R[2] = vmsub(R[2], l20, R[0]);
        D[3] = vmsub(D[3], l30, D[0]); R[3] = vmsub(R[3], l30, R[0]);
        float p1 = D[1][1], i1 = 1.0f / p1;
        float l21 = D[2][1] * i1, l31 = D[3][1] * i1;
        D[2] = vmsub(D[2], l21, D[1]); R[2] = vmsub(R[2], l21, R[1]);
        D[3] = vmsub(D[3], l31, D[1]); R[3] = vmsub(R[3], l31, R[1]);
        float p2 = D[2][2], i2 = 1.0f / p2;
        float l32 = D[3][2] * i2;
        D[3] = vmsub(D[3], l32, D[2]); R[3] = vmsub(R[3], l32, R[2]);
        float p3 = D[3][3], i3 = 1.0f / p3;
        logacc += __log2f(fabsf(p0)) + __log2f(fabsf(p1))
                + __log2f(fabsf(p2)) + __log2f(fabsf(p3));
        float4f X3 = vscale(R[3], i3);
        float4f X2 = vscale(vmsub(R[2], D[2][3], X3), i2);
        float4f X1 = vscale(vmsub(vmsub(R[1], D[1][2], X2), D[1][3], X3), i1);
        float4f X0 = vscale(vmsub(vmsub(vmsub(R[0], D[0][1], X1),
                                        D[0][2], X2), D[0][3], X3), i0);
#pragma unroll
        for (int mg = 0; mg < 4; ++mg) {
#pragma unroll
            for (int e = 0; e < 4; ++e) {
                float4f v = V[mg * 4 + e];
                v = vmsub(v, C[0][mg][e], X0);
                v = vmsub(v, C[1][mg][e], X1);
                v = vmsub(v, C[2][mg][e], X2);
                v = vmsub(v, C[3][mg][e], X3);
                V[mg * 4 + e] = v;
            }
        }
        if (kap < 31) {
            const int nbuf = ((kap + 1) & 1) * 512;
            const int tb = (kap & 1) ? 0 : 4;
            const int mn = (kap + 1) >> 1;
            if (ty >= tb && ty < tb + 4) {
                float4f val;
                switch (mn) {
                case 0:  val = V[0];  break; case 1:  val = V[1];  break;
                case 2:  val = V[2];  break; case 3:  val = V[3];  break;
                case 4:  val = V[4];  break; case 5:  val = V[5];  break;
                case 6:  val = V[6];  break; case 7:  val = V[7];  break;
                case 8:  val = V[8];  break; case 9:  val = V[9];  break;
                case 10: val = V[10]; break; case 11: val = V[11]; break;
                case 12: val = V[12]; break; case 13: val = V[13]; break;
                case 14: val = V[14]; break; default: val = V[15]; break;
                }
                *(float4f*)&rowbuf[nbuf + (ty - tb) * 128 + 4 * tx] = val;
            }
            if (tx == kap + 1) {
#pragma unroll
                for (int j = 0; j < 4; ++j) {
#pragma unroll
                    for (int mg = 0; mg < 4; ++mg) {
                        float4f t = {V[mg * 4 + 0][j], V[mg * 4 + 1][j],
                                     V[mg * 4 + 2][j], V[mg * 4 + 3][j]};
                        *(float4f*)&colbuf[nbuf + j * 128 + ty * 16 + mg * 4] = t;
                    }
                }
            }
        }
        __syncthreads();
    }
    return logacc * LN2;
}

__global__ __launch_bounds__(256, 1) void k_main(
        const void* __restrict__ x,
        const void* __restrict__ W1, const void* __restrict__ b1,
        const void* __restrict__ W2, const void* __restrict__ b2,
        const void* __restrict__ W3, const void* __restrict__ b3,
        void* __restrict__ out, float* __restrict__ ws) {
    extern __shared__ __align__(16) char ldsb[];
    __shared__ int s_last;
    const int tid = threadIdx.x;
    const int lane = tid & 63;
    const int isf32 = detect_f32((const unsigned short*)W1, lane);

    if (blockIdx.x < 12) {
        float ld = isf32 ? lu_logdet<1>(blockIdx.x, tid, (float*)ldsb, W1, W2, W3)
                         : lu_logdet<0>(blockIdx.x, tid, (float*)ldsb, W1, W2, W3);
        if (tid == 0) ws[2 + blockIdx.x] = ld;
    } else {
        const int bid = blockIdx.x - 12;
        if (isf32) fwd<1>(bid, tid, lane, ldsb, x, ws, out, ws);
        else       fwd<0>(bid, tid, lane, ldsb, x, ws, out, ws);
    }

    // ---- last-block finalize ----
    __threadfence();
    if (tid == 0) s_last = (atomicAdd((int*)ws, 1) == NBLK - 1);
    __syncthreads();
    if (!s_last) return;
    __threadfence();   // acquire: other blocks' ws writes now visible
    float s = 0.0f;
#pragma unroll
    for (int i = 0; i < 12; ++i) s += ws[2 + i];
    for (int b = tid; b < 4096; b += 256) {
        float v = s + LOG_SLOPE * ws[64 + b];
        if (isf32) ((float*)out)[524288 + b] = v;
        else ((unsigned short*)out)[524288 + b] = f2bf(v);
    }
}

extern "C" void kernel_launch(void* const* d_in, const int* in_sizes, int n_in,
                              void* d_out, int out_size, void* d_ws, size_t ws_size,
                              hipStream_t stream) {
    const void* x  = d_in[0];
    const void* W1 = d_in[1];
    const void* b1 = d_in[2];
    const void* W2 = d_in[3];
    const void* b2 = d_in[4];
    const void* W3 = d_in[5];
    const void* b3 = d_in[6];
    float* ws = (float*)d_ws;

    hipLaunchKernelGGL(k_prep, dim3(97), dim3(256), 0, stream,
                       W1, W2, W3, b1, b2, b3, ws);
    hipLaunchKernelGGL(k_main, dim3(NBLK), dim3(256), LDS_BYTES, stream,
                       x, W1, b1, W2, b2, W3, b3, d_out, ws);
}